// Round 1
// baseline (11529.493 us; speedup 1.0000x reference)
//
#include <hip/hip_runtime.h>
#include <hip/hip_bf16.h>
#include <stdint.h>

namespace {
constexpr int TP = 400, TQ = 60, NB = 64, NH = 150;
constexpr int H2 = 300, H4 = 600, H8 = 1200;
constexpr int KP150 = 160;   // 150 padded to mult of 8
constexpr int KP300 = 304;   // 300 padded to mult of 8
}

__device__ __forceinline__ float bflo(unsigned int u){ return __uint_as_float(u << 16); }
__device__ __forceinline__ float bfhi(unsigned int u){ return __uint_as_float(u & 0xffff0000u); }
__device__ __forceinline__ float sigm(float x){ return 1.f/(1.f+__expf(-x)); }
__device__ __forceinline__ float tanhf_(float x){ return 1.f - 2.f/(1.f+__expf(2.f*x)); }
__device__ __forceinline__ unsigned short f2bf(float f){
  unsigned int x = __float_as_uint(f);
  x += 0x7fffu + ((x>>16)&1u);
  return (unsigned short)(x>>16);
}

// Convert recurrent weights to bf16, K-padded with zeros.
__global__ __launch_bounds__(256) void k_prep(const float* __restrict__ preWhh,
        const float* __restrict__ ahW, const float* __restrict__ mWih, const float* __restrict__ mWhh,
        unsigned short* __restrict__ whh_b, unsigned short* __restrict__ ah_b,
        unsigned short* __restrict__ ww_b, unsigned short* __restrict__ mwhh_b){
  int i = blockIdx.x*256 + threadIdx.x;
  if (i < H4*KP150){ int r=i/KP150, k=i%KP150; whh_b[i]  = f2bf(k<NH ? preWhh[r*NH+k] : 0.f); }
  if (i < NH*KP150){ int r=i/KP150, k=i%KP150; ah_b[i]   = f2bf(k<NH ? ahW[r*NH+k]   : 0.f); }
  if (i < H4*KP300){ int r=i/KP300, k=i%KP300; ww_b[i]   = f2bf(k<H2 ? mWih[r*H4 + H2 + k] : 0.f); }
  if (i < H4*KP150){ int r=i/KP150, k=i%KP150; mwhh_b[i] = f2bf(k<NH ? mWhh[r*NH+k] : 0.f); }
}

// C[M,N] = gather(A)[M,K] @ W[N,K]^T (+b0[n]) (+b1[n]) (+=C if accum)
// 128x128 tile, BK=8, 256 threads, 8x8 per thread. f32.
__global__ __launch_bounds__(256) void k_gemm(const float* __restrict__ A, const int* __restrict__ ids,
        const float* __restrict__ W, int ldW,
        const float* __restrict__ b0, const float* __restrict__ b1,
        float* __restrict__ C, int M, int N, int K, int accum)
{
  __shared__ float As[8][132];
  __shared__ float Bs[8][132];
  const int tid = threadIdx.x;
  const int m0 = blockIdx.y*128, n0 = blockIdx.x*128;
  const int tm = tid>>4, tn = tid&15;
  const int lr = tid>>1;
  const int lk = (tid&1)*4;
  float acc[8][8];
  #pragma unroll
  for (int i=0;i<8;i++){
    #pragma unroll
    for (int j=0;j<8;j++) acc[i][j]=0.f;
  }
  long arow = -1;
  if (m0 + lr < M) arow = ids ? (long)ids[m0+lr] : (long)(m0+lr);
  const int brow = n0 + lr;
  const bool bok = brow < N;

  for (int k0 = 0; k0 < K; k0 += 8){
    float4 av = make_float4(0.f,0.f,0.f,0.f), bv = make_float4(0.f,0.f,0.f,0.f);
    const int kk = k0 + lk;
    if (arow >= 0){
      if (kk+3 < K) av = *(const float4*)(A + (size_t)arow*K + kk);
      else { float* p=(float*)&av; for(int x=0;x<4;x++) if (kk+x<K) p[x]=A[(size_t)arow*K+kk+x]; }
    }
    if (bok){
      if (kk+3 < K) bv = *(const float4*)(W + (size_t)brow*ldW + kk);
      else { float* p=(float*)&bv; for(int x=0;x<4;x++) if (kk+x<K) p[x]=W[(size_t)brow*ldW+kk+x]; }
    }
    __syncthreads();
    As[lk+0][lr]=av.x; As[lk+1][lr]=av.y; As[lk+2][lr]=av.z; As[lk+3][lr]=av.w;
    Bs[lk+0][lr]=bv.x; Bs[lk+1][lr]=bv.y; Bs[lk+2][lr]=bv.z; Bs[lk+3][lr]=bv.w;
    __syncthreads();
    #pragma unroll
    for (int k=0;k<8;k++){
      float a[8], bb[8];
      float4 t0 = *(const float4*)&As[k][tm*8];
      float4 t1 = *(const float4*)&As[k][tm*8+4];
      a[0]=t0.x; a[1]=t0.y; a[2]=t0.z; a[3]=t0.w; a[4]=t1.x; a[5]=t1.y; a[6]=t1.z; a[7]=t1.w;
      float4 u0 = *(const float4*)&Bs[k][tn*8];
      float4 u1 = *(const float4*)&Bs[k][tn*8+4];
      bb[0]=u0.x; bb[1]=u0.y; bb[2]=u0.z; bb[3]=u0.w; bb[4]=u1.x; bb[5]=u1.y; bb[6]=u1.z; bb[7]=u1.w;
      #pragma unroll
      for (int i=0;i<8;i++){
        #pragma unroll
        for (int j=0;j<8;j++) acc[i][j] += a[i]*bb[j];
      }
    }
  }
  #pragma unroll
  for (int i=0;i<8;i++){
    const int m = m0 + tm*8 + i;
    if (m >= M) continue;
    #pragma unroll
    for (int j=0;j<8;j++){
      const int n = n0 + tn*8 + j;
      if (n >= N) continue;
      float v = acc[i][j];
      if (b0) v += b0[n];
      if (b1) v += b1[n];
      const size_t o = (size_t)m*N + n;
      if (accum) v += C[o];
      C[o] = v;
    }
  }
}

// One WG per (b, dir, passage/question) chain. h,c in LDS. Note: only gates
// i,f,g needed (h is overwritten by tanh(c)); XW is [*,450].
__global__ __launch_bounds__(256) void k_pre_scan(const float* __restrict__ XWp, const float* __restrict__ XWq,
     const unsigned short* __restrict__ whh_b, const int* __restrict__ plens, const int* __restrict__ qlens,
     float* __restrict__ Hp, float* __restrict__ Hq)
{
  const int wg = blockIdx.x;
  const int b = wg & 63;
  const int dir = (wg>>6)&1;
  const int isq = wg>>7;
  const int T = isq ? TQ : TP;
  const float* XW = isq ? XWq : XWp;
  float* Hout = isq ? Hq : Hp;
  const int len = isq ? qlens[b] : plens[b];
  const int tid = threadIdx.x;
  __shared__ float h[KP150];
  __shared__ float c[NH];
  __shared__ float g[456];
  if (tid < KP150) h[tid] = 0.f;
  if (tid < NH) c[tid] = 0.f;
  __syncthreads();
  for (int s=0; s<T; s++){
    const int t = dir ? (T-1-s) : s;
    const bool act = t < len;
    if (act){
      const float* xw = XW + (size_t)(t*NB + b)*450;
      for (int j = tid; j < 450; j += 256){
        const uint4* wr = (const uint4*)(whh_b + (size_t)j*KP150);
        float acc = xw[j];
        #pragma unroll 5
        for (int kb=0; kb<KP150/8; kb++){
          uint4 u = wr[kb];
          const float4* hv = (const float4*)&h[kb*8];
          float4 h0 = hv[0], h1 = hv[1];
          acc += bflo(u.x)*h0.x + bfhi(u.x)*h0.y + bflo(u.y)*h0.z + bfhi(u.y)*h0.w
               + bflo(u.z)*h1.x + bfhi(u.z)*h1.y + bflo(u.w)*h1.z + bfhi(u.w)*h1.w;
        }
        g[j] = acc;
      }
    }
    __syncthreads();
    if (tid < NH){
      float h2 = 0.f, c2 = 0.f;
      if (act){
        const float gi = sigm(g[tid]);
        const float gf = sigm(g[NH+tid]);
        const float gg = tanhf_(g[2*NH+tid]);
        c2 = gf*c[tid] + gi*gg;
        h2 = tanhf_(c2);
      }
      h[tid] = h2; c[tid] = c2;
      Hout[(size_t)(t*NB+b)*H2 + dir*NH + tid] = h2;
    }
    __syncthreads();
  }
}

// Match-LSTM: one WG(512) per (b, dir). attq/Hq slices cached in LDS (bf16).
__global__ __launch_bounds__(512) void k_match(const float* __restrict__ ATTQ, const float* __restrict__ APP,
    const float* __restrict__ HPW, const float* __restrict__ Hq,
    const unsigned short* __restrict__ ww_b, const unsigned short* __restrict__ mwhh_b,
    const unsigned short* __restrict__ ah_b,
    const float* __restrict__ alW, const int* __restrict__ plens, float* __restrict__ Hr)
{
  const int wg = blockIdx.x;
  const int b = wg & 63;
  const int dir = wg >> 6;
  const int tid = threadIdx.x;
  __shared__ unsigned short aq_b[TQ*152];
  __shared__ unsigned short hq_b[TQ*KP300];
  __shared__ float h[KP150];
  __shared__ float c[NH];
  __shared__ float w[KP300];
  __shared__ float hw[NH];
  __shared__ float gp[H4];
  __shared__ float ap[NH];
  __shared__ float alws[NH];
  __shared__ float sp[TQ][4];
  __shared__ float alpha[TQ];

  for (int i = tid; i < TQ*NH; i += 512){
    int tq = i/NH, k = i%NH;
    aq_b[tq*152+k] = f2bf(ATTQ[(size_t)(tq*NB+b)*NH + k]);
  }
  for (int i = tid; i < TQ*KP300; i += 512){
    int tq = i/KP300, k = i%KP300;
    hq_b[i] = f2bf(k<H2 ? Hq[(size_t)(tq*NB+b)*H2 + k] : 0.f);
  }
  if (tid < KP150) h[tid]=0.f;
  if (tid < NH) c[tid]=0.f;
  if (tid < KP300) w[tid]=0.f;
  if (tid < NH) alws[tid] = alW[tid];
  const int len = plens[b];
  __syncthreads();

  for (int s=0; s<TP; s++){
    const int t = dir ? (TP-1-s) : s;
    const bool act = t < len;
    if (!act){
      if (tid < KP150) h[tid]=0.f;
      if (tid < NH){ c[tid]=0.f; Hr[(size_t)(t*NB+b)*H2 + dir*NH + tid] = 0.f; }
      __syncthreads();
      continue;
    }
    if (tid < NH) ap[tid] = APP[(size_t)(t*NB+b)*NH + tid];
    // phase A: hw = h@ah^T (150 rows), gp = h@Whh^T (600 rows)
    for (int j = tid; j < 750; j += 512){
      const uint4* wr = (j < NH) ? (const uint4*)(ah_b + (size_t)j*KP150)
                                 : (const uint4*)(mwhh_b + (size_t)(j-NH)*KP150);
      float acc = 0.f;
      #pragma unroll 5
      for (int kb=0; kb<KP150/8; kb++){
        uint4 u = wr[kb];
        const float4* hv = (const float4*)&h[kb*8];
        float4 h0=hv[0], h1=hv[1];
        acc += bflo(u.x)*h0.x + bfhi(u.x)*h0.y + bflo(u.y)*h0.z + bfhi(u.y)*h0.w
             + bflo(u.z)*h1.x + bfhi(u.z)*h1.y + bflo(u.w)*h1.z + bfhi(u.w)*h1.w;
      }
      if (j < NH) hw[j] = acc; else gp[j-NH] = acc;
    }
    __syncthreads();
    // phase B: attention scores over tq (al_b dropped - softmax invariant)
    if (tid < 240){
      const int tq = tid>>2, q = tid&3;
      const int k0 = q*38, k1 = (q==3)? NH : (k0+38);
      float acc = 0.f;
      for (int k=k0; k<k1; k+=2){
        unsigned int u = *(const unsigned int*)&aq_b[tq*152 + k];
        acc += alws[k]  * tanhf_(bflo(u) + ap[k]   + hw[k]);
        acc += alws[k+1]* tanhf_(bfhi(u) + ap[k+1] + hw[k+1]);
      }
      sp[tq][q] = acc;
    }
    __syncthreads();
    // phase C: softmax over 60 (wave 0)
    if (tid < 64){
      float sv = (tid<TQ)? (sp[tid][0]+sp[tid][1]+sp[tid][2]+sp[tid][3]) : -1e30f;
      float mx = sv;
      #pragma unroll
      for (int o=32;o;o>>=1) mx = fmaxf(mx, __shfl_xor(mx,o));
      float e = (tid<TQ)? __expf(sv-mx) : 0.f;
      float sm = e;
      #pragma unroll
      for (int o=32;o;o>>=1) sm += __shfl_xor(sm,o);
      if (tid<TQ) alpha[tid] = e/sm;
    }
    __syncthreads();
    // phase C2: w = sum alpha * Hq
    for (int jj = tid; jj < NH; jj += 512){
      const int j = jj*2;
      float a0=0.f, a1=0.f;
      for (int tq=0; tq<TQ; tq++){
        unsigned int u = *(const unsigned int*)&hq_b[tq*KP300 + j];
        const float al = alpha[tq];
        a0 += al*bflo(u); a1 += al*bfhi(u);
      }
      w[j]=a0; w[j+1]=a1;
    }
    __syncthreads();
    // phase D: gates = hpW + h@Whh (gp) + w@WihR
    {
      const float* hpw = HPW + (size_t)(t*NB+b)*H4;
      for (int j = tid; j < H4; j += 512){
        const uint4* wr = (const uint4*)(ww_b + (size_t)j*KP300);
        float acc = hpw[j] + gp[j];
        #pragma unroll 2
        for (int kb=0; kb<KP300/8; kb++){
          uint4 u = wr[kb];
          const float4* wv = (const float4*)&w[kb*8];
          float4 w0=wv[0], w1=wv[1];
          acc += bflo(u.x)*w0.x + bfhi(u.x)*w0.y + bflo(u.y)*w0.z + bfhi(u.y)*w0.w
               + bflo(u.z)*w1.x + bfhi(u.z)*w1.y + bflo(u.w)*w1.z + bfhi(u.w)*w1.w;
        }
        gp[j] = acc;  // in-place
      }
    }
    __syncthreads();
    // phase E: LSTM cell update
    if (tid < NH){
      const float gi = sigm(gp[tid]);
      const float gf = sigm(gp[NH+tid]);
      const float gg = tanhf_(gp[2*NH+tid]);
      const float go = sigm(gp[3*NH+tid]);
      const float c2 = gf*c[tid] + gi*gg;
      const float h2 = go*tanhf_(c2);
      c[tid]=c2; h[tid]=h2;
      Hr[(size_t)(t*NB+b)*H2 + dir*NH + tid] = h2;
    }
    __syncthreads();
  }
}

// alpha_q / wq (ala_b dropped - softmax invariant). Also fills wq halves of WRWQ.
__global__ __launch_bounds__(256) void k_wq(const float* __restrict__ AQA, const float* __restrict__ Hq,
        const float* __restrict__ alaW, float* __restrict__ wqb, float* __restrict__ WRWQ)
{
  const int b = blockIdx.x;
  const int tid = threadIdx.x;
  __shared__ float sp[TQ][4];
  __shared__ float alpha[TQ];
  __shared__ float alw[NH];
  if (tid < NH) alw[tid] = alaW[tid];
  __syncthreads();
  if (tid < 240){
    const int tq = tid>>2, q = tid&3;
    const int k0=q*38, k1=(q==3)?NH:(k0+38);
    float acc=0.f;
    for (int k=k0;k<k1;k++)
      acc += alw[k]*tanhf_(AQA[(size_t)(tq*NB+b)*NH + k]);
    sp[tq][q]=acc;
  }
  __syncthreads();
  if (tid < 64){
    float sv = (tid<TQ)? (sp[tid][0]+sp[tid][1]+sp[tid][2]+sp[tid][3]) : -1e30f;
    float mx = sv;
    #pragma unroll
    for (int o=32;o;o>>=1) mx = fmaxf(mx, __shfl_xor(mx,o));
    float e = (tid<TQ)? __expf(sv-mx) : 0.f;
    float sm = e;
    #pragma unroll
    for (int o=32;o;o>>=1) sm += __shfl_xor(sm,o);
    if (tid<TQ) alpha[tid] = e/sm;
  }
  __syncthreads();
  for (int j=tid; j<H2; j+=256){
    float acc=0.f;
    for (int tq=0;tq<TQ;tq++) acc += alpha[tq]*Hq[(size_t)(tq*NB+b)*H2 + j];
    wqb[b*H2+j] = acc;
    WRWQ[(size_t)b*H4 + H2 + j] = acc;
    WRWQ[(size_t)(NB+b)*H4 + H2 + j] = acc;
  }
}

// Pointer scores: sf = btW . tanh(aml + haW + wq) + btb.  One wave per (dir,t,b) row.
__global__ __launch_bounds__(256) void k_F(const float* __restrict__ AML, const float* __restrict__ AMLB,
      const float* __restrict__ HAW, const float* __restrict__ wqb,
      const float* __restrict__ btW, const float* __restrict__ btb, float* __restrict__ SF)
{
  const int gr = blockIdx.x*4 + (threadIdx.x>>6);
  const int lane = threadIdx.x & 63;
  const int dir = gr / (TP*NB);
  const int rem = gr % (TP*NB);
  const int b = rem % NB;
  const float* mrow = (dir? AMLB : AML) + (size_t)rem*H2;
  const float* hrow = HAW + (size_t)(dir*NB + b)*H2;
  const float* wrow = wqb + (size_t)b*H2;
  float acc = 0.f;
  for (int j = lane; j < H2; j += 64)
    acc += btW[j]*tanhf_(mrow[j] + hrow[j] + wrow[j]);
  #pragma unroll
  for (int o=32;o;o>>=1) acc += __shfl_xor(acc,o);
  if (lane==0) SF[gr] = acc + btb[0];
}

// Masked softmax over Tp, write dists (k>=1), compute wr (k<2).
__global__ __launch_bounds__(256) void k_beta(const float* __restrict__ SF, const float* __restrict__ Hr,
     const int* __restrict__ plens, float* __restrict__ WRWQ, float* __restrict__ dout, int kidx)
{
  const int wg = blockIdx.x; const int b = wg&63; const int dir = wg>>6;
  const int tid = threadIdx.x;
  __shared__ float sv[TP];
  __shared__ float red[256];
  const int len = plens[b];
  for (int t=tid;t<TP;t+=256) sv[t] = SF[(size_t)dir*TP*NB + t*NB + b];
  __syncthreads();
  float mx = -1e30f;
  for (int t=tid;t<len;t+=256) mx = fmaxf(mx, sv[t]);
  red[tid]=mx; __syncthreads();
  for (int o=128;o;o>>=1){ if (tid<o) red[tid]=fmaxf(red[tid],red[tid+o]); __syncthreads(); }
  mx = red[0]; __syncthreads();
  float sm=0.f;
  for (int t=tid;t<len;t+=256) sm += __expf(sv[t]-mx);
  red[tid]=sm; __syncthreads();
  for (int o=128;o;o>>=1){ if (tid<o) red[tid]+=red[tid+o]; __syncthreads(); }
  const float inv = 1.f/red[0];
  __syncthreads();
  for (int t=tid;t<TP;t+=256){
    const float bt = (t<len)? __expf(sv[t]-mx)*inv : 0.f;
    sv[t] = bt;
    if (kidx>0) dout[(size_t)(dir*2 + kidx-1)*TP*NB + (size_t)b*TP + t] = bt;
  }
  __syncthreads();
  if (kidx < 2){
    for (int j=tid;j<H2;j+=256){
      float acc=0.f;
      for (int t=0;t<TP;t++) acc += sv[t]*Hr[(size_t)(t*NB+b)*H2 + j];
      WRWQ[(size_t)(dir*NB+b)*H4 + j] = acc;
    }
  }
}

__global__ __launch_bounds__(256) void k_cell(const float* __restrict__ G, float* __restrict__ Sh, float* __restrict__ Sc){
  const int i = blockIdx.x*256+threadIdx.x;
  if (i >= 128*H2) return;
  const int r = i/H2, j = i%H2;
  const float* gr = G + (size_t)r*H8;
  const float gi=sigm(gr[j]), gf=sigm(gr[H2+j]), gg=tanhf_(gr[2*H2+j]), go=sigm(gr[3*H2+j]);
  const float c2 = gf*Sc[i] + gi*gg;
  Sc[i]=c2; Sh[i]=go*tanhf_(c2);
}

extern "C" void kernel_launch(void* const* d_in, const int* in_sizes, int n_in,
                              void* d_out, int out_size, void* d_ws, size_t ws_size,
                              hipStream_t stream)
{
  const int* p_ids = (const int*)d_in[0];
  const int* q_ids = (const int*)d_in[1];
  const int* p_len = (const int*)d_in[2];
  const int* q_len = (const int*)d_in[3];
  const float* emb    = (const float*)d_in[4];
  const float* preWih = (const float*)d_in[5];
  const float* preWhh = (const float*)d_in[6];
  const float* preBih = (const float*)d_in[7];
  const float* preBhh = (const float*)d_in[8];
  const float* aqW  = (const float*)d_in[9];
  const float* apW  = (const float*)d_in[10];
  const float* apB  = (const float*)d_in[11];
  const float* ahW  = (const float*)d_in[12];
  const float* alWp = (const float*)d_in[13];
  // d_in[14] al_b: softmax-invariant, unused
  const float* mWih = (const float*)d_in[15];
  const float* mWhh = (const float*)d_in[16];
  const float* mBih = (const float*)d_in[17];
  const float* mBhh = (const float*)d_in[18];
  const float* aqaW = (const float*)d_in[19];
  const float* alaW = (const float*)d_in[20];
  // d_in[21] ala_b: softmax-invariant, unused
  const float* amlW  = (const float*)d_in[22];
  const float* amlbW = (const float*)d_in[23];
  const float* aansW = (const float*)d_in[24];
  const float* aansB = (const float*)d_in[25];
  const float* btW = (const float*)d_in[26];
  const float* btB = (const float*)d_in[27];
  const float* ansWih = (const float*)d_in[28];
  const float* ansWhh = (const float*)d_in[29];
  const float* ansBih = (const float*)d_in[30];
  const float* ansBhh = (const float*)d_in[31];
  float* out = (float*)d_out;

  char* base = (char*)d_ws;
  size_t off = 0;
  auto alloc = [&](size_t bytes)->char*{ char* r = base+off; off += (bytes+255)&~(size_t)255; return r; };
  float* BIG  = (float*)alloc((size_t)TP*NB*H4*4);   // XWp(450w) -> HPW(600w) -> AML|AMLB
  float* XWQ  = (float*)alloc((size_t)TQ*NB*450*4);
  float* HP   = (float*)alloc((size_t)TP*NB*H2*4);
  float* HQ   = (float*)alloc((size_t)TQ*NB*H2*4);
  float* ATTQ = (float*)alloc((size_t)TQ*NB*NH*4);
  float* APP  = (float*)alloc((size_t)TP*NB*NH*4);
  float* HR   = (float*)alloc((size_t)TP*NB*H2*4);
  float* AQA  = (float*)alloc((size_t)TQ*NB*NH*4);
  float* SFb  = (float*)alloc((size_t)2*TP*NB*4);
  float* WRWQ = (float*)alloc((size_t)128*H4*4);
  float* HAW  = (float*)alloc((size_t)128*H2*4);
  float* Gb   = (float*)alloc((size_t)128*H8*4);
  float* Sh   = (float*)alloc((size_t)128*H2*4);
  float* Sc   = (float*)alloc((size_t)128*H2*4);
  float* WQB  = (float*)alloc((size_t)NB*H2*4);
  unsigned short* whh_b  = (unsigned short*)alloc((size_t)H4*KP150*2);
  unsigned short* ah_b   = (unsigned short*)alloc((size_t)NH*KP150*2);
  unsigned short* ww_b   = (unsigned short*)alloc((size_t)H4*KP300*2);
  unsigned short* mwhh_b = (unsigned short*)alloc((size_t)H4*KP150*2);
  float* AML  = BIG;
  float* AMLB = BIG + (size_t)TP*NB*H2;

  dim3 blk(256);
  k_prep<<<(H4*KP300+255)/256, blk, 0, stream>>>(preWhh, ahW, mWih, mWhh, whh_b, ah_b, ww_b, mwhh_b);
  // XW = emb[ids] @ preWih^T + bih + bhh   (only i,f,g gate columns: N=450)
  { dim3 g((450+127)/128, (TP*NB+127)/128);
    k_gemm<<<g, blk, 0, stream>>>(emb, p_ids, preWih, H2, preBih, preBhh, BIG, TP*NB, 450, H2, 0); }
  { dim3 g((450+127)/128, (TQ*NB+127)/128);
    k_gemm<<<g, blk, 0, stream>>>(emb, q_ids, preWih, H2, preBih, preBhh, XWQ, TQ*NB, 450, H2, 0); }
  k_pre_scan<<<256, blk, 0, stream>>>(BIG, XWQ, whh_b, p_len, q_len, HP, HQ);
  { dim3 g((NH+127)/128, (TQ*NB+127)/128);
    k_gemm<<<g,blk,0,stream>>>(HQ, nullptr, aqW, H2, nullptr, nullptr, ATTQ, TQ*NB, NH, H2, 0); }
  { dim3 g((NH+127)/128, (TP*NB+127)/128);
    k_gemm<<<g,blk,0,stream>>>(HP, nullptr, apW, H2, apB, nullptr, APP, TP*NB, NH, H2, 0); }
  { dim3 g((H4+127)/128, (TP*NB+127)/128);
    k_gemm<<<g,blk,0,stream>>>(HP, nullptr, mWih, H4, mBih, mBhh, BIG, TP*NB, H4, H2, 0); }
  { dim3 g((NH+127)/128, (TQ*NB+127)/128);
    k_gemm<<<g,blk,0,stream>>>(HQ, nullptr, aqaW, H2, nullptr, nullptr, AQA, TQ*NB, NH, H2, 0); }
  k_wq<<<NB, blk, 0, stream>>>(AQA, HQ, alaW, WQB, WRWQ);
  k_match<<<dim3(128), dim3(512), 0, stream>>>(ATTQ, APP, BIG, HQ, ww_b, mwhh_b, ah_b, alWp, p_len, HR);
  { dim3 g((H2+127)/128, (TP*NB+127)/128);
    k_gemm<<<g,blk,0,stream>>>(HR, nullptr, amlW,  H2, nullptr, nullptr, AML,  TP*NB, H2, H2, 0);
    k_gemm<<<g,blk,0,stream>>>(HR, nullptr, amlbW, H2, nullptr, nullptr, AMLB, TP*NB, H2, H2, 0); }
  hipMemsetAsync(Sh, 0, (size_t)128*H2*4, stream);
  hipMemsetAsync(Sc, 0, (size_t)128*H2*4, stream);
  for (int k=0;k<3;k++){
    { dim3 g((H2+127)/128, 1);
      k_gemm<<<g,blk,0,stream>>>(Sh, nullptr, aansW, H2, aansB, nullptr, HAW, 128, H2, H2, 0); }
    k_F<<<(2*TP*NB)/4, blk, 0, stream>>>(AML, AMLB, HAW, WQB, btW, btB, SFb);
    k_beta<<<128, blk, 0, stream>>>(SFb, HR, p_len, WRWQ, out, k);
    if (k<2){
      { dim3 g((H8+127)/128, 1);
        k_gemm<<<g,blk,0,stream>>>(WRWQ, nullptr, ansWih, H4, ansBih, ansBhh, Gb, 128, H8, H4, 0); }
      { dim3 g((H8+127)/128, 1);
        k_gemm<<<g,blk,0,stream>>>(Sh, nullptr, ansWhh, H2, nullptr, nullptr, Gb, 128, H8, H2, 1); }
      k_cell<<<(128*H2+255)/256, blk, 0, stream>>>(Gb, Sh, Sc);
    }
  }
}

// Round 2
// 7117.064 us; speedup vs baseline: 1.6200x; 1.6200x over previous
//
#include <hip/hip_runtime.h>
#include <hip/hip_bf16.h>
#include <stdint.h>

namespace {
constexpr int TP = 400, TQ = 60, NB = 64, NH = 150;
constexpr int H2 = 300, H4 = 600, H8 = 1200;
constexpr int KP150 = 160;   // 150 padded to mult of 8
}

__device__ __forceinline__ float bflo(unsigned int u){ return __uint_as_float(u << 16); }
__device__ __forceinline__ float bfhi(unsigned int u){ return __uint_as_float(u & 0xffff0000u); }
__device__ __forceinline__ float sigm(float x){ return 1.f/(1.f+__expf(-x)); }
__device__ __forceinline__ float tanhf_(float x){ return 1.f - 2.f/(1.f+__expf(2.f*x)); }
__device__ __forceinline__ unsigned short f2bf(float f){
  unsigned int x = __float_as_uint(f);
  x += 0x7fffu + ((x>>16)&1u);
  return (unsigned short)(x>>16);
}

// Convert recurrent weights to bf16, K-padded with zeros.
__global__ __launch_bounds__(256) void k_prep(const float* __restrict__ preWhh,
        const float* __restrict__ ahW, const float* __restrict__ mWhh,
        unsigned short* __restrict__ whh_b, unsigned short* __restrict__ ah_b,
        unsigned short* __restrict__ mwhh_b){
  int i = blockIdx.x*256 + threadIdx.x;
  if (i < H4*KP150){ int r=i/KP150, k=i%KP150; whh_b[i]  = f2bf(k<NH ? preWhh[r*NH+k] : 0.f); }
  if (i < NH*KP150){ int r=i/KP150, k=i%KP150; ah_b[i]   = f2bf(k<NH ? ahW[r*NH+k]   : 0.f); }
  if (i < H4*KP150){ int r=i/KP150, k=i%KP150; mwhh_b[i] = f2bf(k<NH ? mWhh[r*NH+k] : 0.f); }
}

// QWT[b][j][tq(pad64)] = bf16( QWf[(tq*NB+b)*H4 + j] )
__global__ __launch_bounds__(256) void k_qwt(const float* __restrict__ QWf, unsigned short* __restrict__ QWT){
  int i = blockIdx.x*256 + threadIdx.x;
  if (i >= NB*H4*64) return;
  int tq = i & 63;
  int j  = (i >> 6) % H4;
  int b  = i / (H4*64);
  QWT[i] = f2bf(tq < TQ ? QWf[(size_t)(tq*NB + b)*H4 + j] : 0.f);
}

// C[M,N] = gather(A)[M,K] @ W[N,K]^T (+b0[n]) (+b1[n]) (+=C if accum)
__global__ __launch_bounds__(256) void k_gemm(const float* __restrict__ A, const int* __restrict__ ids,
        const float* __restrict__ W, int ldW,
        const float* __restrict__ b0, const float* __restrict__ b1,
        float* __restrict__ C, int M, int N, int K, int accum)
{
  __shared__ float As[8][132];
  __shared__ float Bs[8][132];
  const int tid = threadIdx.x;
  const int m0 = blockIdx.y*128, n0 = blockIdx.x*128;
  const int tm = tid>>4, tn = tid&15;
  const int lr = tid>>1;
  const int lk = (tid&1)*4;
  float acc[8][8];
  #pragma unroll
  for (int i=0;i<8;i++){
    #pragma unroll
    for (int j=0;j<8;j++) acc[i][j]=0.f;
  }
  long arow = -1;
  if (m0 + lr < M) arow = ids ? (long)ids[m0+lr] : (long)(m0+lr);
  const int brow = n0 + lr;
  const bool bok = brow < N;

  for (int k0 = 0; k0 < K; k0 += 8){
    float4 av = make_float4(0.f,0.f,0.f,0.f), bv = make_float4(0.f,0.f,0.f,0.f);
    const int kk = k0 + lk;
    if (arow >= 0){
      if (kk+3 < K) av = *(const float4*)(A + (size_t)arow*K + kk);
      else { float* p=(float*)&av; for(int x=0;x<4;x++) if (kk+x<K) p[x]=A[(size_t)arow*K+kk+x]; }
    }
    if (bok){
      if (kk+3 < K) bv = *(const float4*)(W + (size_t)brow*ldW + kk);
      else { float* p=(float*)&bv; for(int x=0;x<4;x++) if (kk+x<K) p[x]=W[(size_t)brow*ldW+kk+x]; }
    }
    __syncthreads();
    As[lk+0][lr]=av.x; As[lk+1][lr]=av.y; As[lk+2][lr]=av.z; As[lk+3][lr]=av.w;
    Bs[lk+0][lr]=bv.x; Bs[lk+1][lr]=bv.y; Bs[lk+2][lr]=bv.z; Bs[lk+3][lr]=bv.w;
    __syncthreads();
    #pragma unroll
    for (int k=0;k<8;k++){
      float a[8], bb[8];
      float4 t0 = *(const float4*)&As[k][tm*8];
      float4 t1 = *(const float4*)&As[k][tm*8+4];
      a[0]=t0.x; a[1]=t0.y; a[2]=t0.z; a[3]=t0.w; a[4]=t1.x; a[5]=t1.y; a[6]=t1.z; a[7]=t1.w;
      float4 u0 = *(const float4*)&Bs[k][tn*8];
      float4 u1 = *(const float4*)&Bs[k][tn*8+4];
      bb[0]=u0.x; bb[1]=u0.y; bb[2]=u0.z; bb[3]=u0.w; bb[4]=u1.x; bb[5]=u1.y; bb[6]=u1.z; bb[7]=u1.w;
      #pragma unroll
      for (int i=0;i<8;i++){
        #pragma unroll
        for (int j=0;j<8;j++) acc[i][j] += a[i]*bb[j];
      }
    }
  }
  #pragma unroll
  for (int i=0;i<8;i++){
    const int m = m0 + tm*8 + i;
    if (m >= M) continue;
    #pragma unroll
    for (int j=0;j<8;j++){
      const int n = n0 + tn*8 + j;
      if (n >= N) continue;
      float v = acc[i][j];
      if (b0) v += b0[n];
      if (b1) v += b1[n];
      const size_t o = (size_t)m*N + n;
      if (accum) v += C[o];
      C[o] = v;
    }
  }
}

// One WG(512) per (b, dir, passage/question) chain. 1 row/thread.
__global__ __launch_bounds__(512) void k_pre_scan(const float* __restrict__ XWp, const float* __restrict__ XWq,
     const unsigned short* __restrict__ whh_b, const int* __restrict__ plens, const int* __restrict__ qlens,
     float* __restrict__ Hp, float* __restrict__ Hq)
{
  const int wg = blockIdx.x;
  const int b = wg & 63;
  const int dir = (wg>>6)&1;
  const int isq = wg>>7;
  const int T = isq ? TQ : TP;
  const float* XW = isq ? XWq : XWp;
  float* Hout = isq ? Hq : Hp;
  const int len = isq ? qlens[b] : plens[b];
  const int tid = threadIdx.x;
  __shared__ float h[KP150];
  __shared__ float c[NH];
  __shared__ float g[456];
  if (tid < KP150) h[tid] = 0.f;
  if (tid < NH) c[tid] = 0.f;
  __syncthreads();
  for (int s=0; s<T; s++){
    const int t = dir ? (T-1-s) : s;
    const bool act = t < len;
    if (act && tid < 450){
      const uint4* wr = (const uint4*)(whh_b + (size_t)tid*KP150);
      float acc = XW[(size_t)(t*NB + b)*450 + tid];
      #pragma unroll 5
      for (int kb=0; kb<KP150/8; kb++){
        uint4 u = wr[kb];
        const float4* hv = (const float4*)&h[kb*8];
        float4 h0 = hv[0], h1 = hv[1];
        acc += bflo(u.x)*h0.x + bfhi(u.x)*h0.y + bflo(u.y)*h0.z + bfhi(u.y)*h0.w
             + bflo(u.z)*h1.x + bfhi(u.z)*h1.y + bflo(u.w)*h1.z + bfhi(u.w)*h1.w;
      }
      g[tid] = acc;
    }
    __syncthreads();
    if (tid < NH){
      float h2 = 0.f, c2 = 0.f;
      if (act){
        const float gi = sigm(g[tid]);
        const float gf = sigm(g[NH+tid]);
        const float gg = tanhf_(g[2*NH+tid]);
        c2 = gf*c[tid] + gi*gg;
        h2 = tanhf_(c2);
      }
      h[tid] = h2; c[tid] = c2;
      Hout[(size_t)(t*NB+b)*H2 + dir*NH + tid] = h2;
    }
    __syncthreads();
  }
}

// Match-LSTM: one WG(1024) per (b, dir).
// Per-thread-persistent QW row (bf16, 8xuint4) replaces the per-step w@Wih_r dot.
__global__ __launch_bounds__(1024) void k_match(const float* __restrict__ ATTQ, const float* __restrict__ APP,
    const float* __restrict__ HPW, const unsigned short* __restrict__ QWT,
    const unsigned short* __restrict__ mwhh_b, const unsigned short* __restrict__ ah_b,
    const float* __restrict__ alW, const int* __restrict__ plens, float* __restrict__ Hr)
{
  const int wg = blockIdx.x;
  const int b = wg & 63;
  const int dir = wg >> 6;
  const int tid = threadIdx.x;
  __shared__ unsigned short aq_b[TQ*152];  // 18.2 KB
  __shared__ float h[KP150];
  __shared__ float c[NH];
  __shared__ float hw[152];
  __shared__ float gp[H4];
  __shared__ float ap[152];
  __shared__ float alws[NH];
  __shared__ float sp[TQ][16];
  __shared__ float alpha[TQ];

  for (int i = tid; i < TQ*NH; i += 1024){
    int tq = i/NH, k = i%NH;
    aq_b[tq*152+k] = f2bf(ATTQ[(size_t)(tq*NB+b)*NH + k]);
  }
  if (tid < KP150) h[tid]=0.f;
  if (tid < NH){ c[tid]=0.f; alws[tid] = alW[tid]; }
  const int len = plens[b];

  // persistent QW row for this thread's gate output j=tid (tid<600): 64 bf16
  uint4 qv[8];
  if (tid < H4){
    const uint4* qp = (const uint4*)(QWT + ((size_t)b*H4 + tid)*64);
    #pragma unroll
    for (int x=0;x<8;x++) qv[x] = qp[x];
  }
  __syncthreads();

  for (int s=0; s<TP; s++){
    const int t = dir ? (TP-1-s) : s;
    const bool act = t < len;
    if (!act){
      if (tid < KP150) h[tid]=0.f;
      if (tid < NH){ c[tid]=0.f; Hr[(size_t)(t*NB+b)*H2 + dir*NH + tid] = 0.f; }
      __syncthreads();
      continue;
    }
    // phase A: threads 0..599 -> gp_j = hpw_j + h.mwhh_j (kept in register);
    //          threads 600..749 -> hw_j = h.ah_j ; also stage ap.
    float gpr = 0.f;
    if (tid < H4){
      const uint4* wr = (const uint4*)(mwhh_b + (size_t)tid*KP150);
      float acc = HPW[(size_t)(t*NB+b)*H4 + tid];
      #pragma unroll 5
      for (int kb=0; kb<KP150/8; kb++){
        uint4 u = wr[kb];
        const float4* hv = (const float4*)&h[kb*8];
        float4 h0=hv[0], h1=hv[1];
        acc += bflo(u.x)*h0.x + bfhi(u.x)*h0.y + bflo(u.y)*h0.z + bfhi(u.y)*h0.w
             + bflo(u.z)*h1.x + bfhi(u.z)*h1.y + bflo(u.w)*h1.z + bfhi(u.w)*h1.w;
      }
      gpr = acc;
    } else if (tid < 750){
      const int j = tid - H4;
      ap[j] = APP[(size_t)(t*NB+b)*NH + j];
      const uint4* wr = (const uint4*)(ah_b + (size_t)j*KP150);
      float acc = 0.f;
      #pragma unroll 5
      for (int kb=0; kb<KP150/8; kb++){
        uint4 u = wr[kb];
        const float4* hv = (const float4*)&h[kb*8];
        float4 h0=hv[0], h1=hv[1];
        acc += bflo(u.x)*h0.x + bfhi(u.x)*h0.y + bflo(u.y)*h0.z + bfhi(u.y)*h0.w
             + bflo(u.z)*h1.x + bfhi(u.z)*h1.y + bflo(u.w)*h1.z + bfhi(u.w)*h1.w;
      }
      hw[j] = acc;
    }
    __syncthreads();
    // phase B: 900 threads: (tq, slice of 10 k's)
    if (tid < 900){
      const int tq = tid/15, sl = tid%15;
      const int k0 = sl*10;
      float acc = 0.f;
      #pragma unroll
      for (int kk=0; kk<10; kk+=2){
        const int k = k0+kk;
        unsigned int u = *(const unsigned int*)&aq_b[tq*152 + k];
        acc += alws[k]  * tanhf_(bflo(u) + ap[k]   + hw[k]);
        acc += alws[k+1]* tanhf_(bfhi(u) + ap[k+1] + hw[k+1]);
      }
      sp[tq][sl] = acc;
    }
    __syncthreads();
    // phase C: softmax over 60 (wave 0)
    if (tid < 64){
      float sv = -1e30f;
      if (tid < TQ){
        sv = 0.f;
        #pragma unroll
        for (int sl=0; sl<15; sl++) sv += sp[tid][sl];
      }
      float mx = sv;
      #pragma unroll
      for (int o=32;o;o>>=1) mx = fmaxf(mx, __shfl_xor(mx,o));
      float e = (tid<TQ)? __expf(sv-mx) : 0.f;
      float sm = e;
      #pragma unroll
      for (int o=32;o;o>>=1) sm += __shfl_xor(sm,o);
      if (tid<TQ) alpha[tid] = e/sm;
    }
    __syncthreads();
    // phase D: gates_j = gpr + sum_tq alpha[tq]*QW[b][j][tq]  (registers + LDS only)
    if (tid < H4){
      float acc = gpr;
      #pragma unroll
      for (int x=0;x<8;x++){
        const int base = x*8;
        if (base+1 < TQ) acc += alpha[base+0]*bflo(qv[x].x) + alpha[base+1]*bfhi(qv[x].x);
        if (base+3 < TQ) acc += alpha[base+2]*bflo(qv[x].y) + alpha[base+3]*bfhi(qv[x].y);
        if (base+5 < TQ) acc += alpha[base+4]*bflo(qv[x].z) + alpha[base+5]*bfhi(qv[x].z);
        if (base+7 < TQ) acc += alpha[base+6]*bflo(qv[x].w) + alpha[base+7]*bfhi(qv[x].w);
      }
      gp[tid] = acc;
    }
    __syncthreads();
    // phase E: cell update
    if (tid < NH){
      const float gi = sigm(gp[tid]);
      const float gf = sigm(gp[NH+tid]);
      const float gg = tanhf_(gp[2*NH+tid]);
      const float go = sigm(gp[3*NH+tid]);
      const float c2 = gf*c[tid] + gi*gg;
      const float h2 = go*tanhf_(c2);
      c[tid]=c2; h[tid]=h2;
      Hr[(size_t)(t*NB+b)*H2 + dir*NH + tid] = h2;
    }
    __syncthreads();
  }
}

// alpha_q / wq (ala_b dropped - softmax invariant). Also fills wq halves of WRWQ.
__global__ __launch_bounds__(256) void k_wq(const float* __restrict__ AQA, const float* __restrict__ Hq,
        const float* __restrict__ alaW, float* __restrict__ wqb, float* __restrict__ WRWQ)
{
  const int b = blockIdx.x;
  const int tid = threadIdx.x;
  __shared__ float sp[TQ][4];
  __shared__ float alpha[TQ];
  __shared__ float alw[NH];
  if (tid < NH) alw[tid] = alaW[tid];
  __syncthreads();
  if (tid < 240){
    const int tq = tid>>2, q = tid&3;
    const int k0=q*38, k1=(q==3)?NH:(k0+38);
    float acc=0.f;
    for (int k=k0;k<k1;k++)
      acc += alw[k]*tanhf_(AQA[(size_t)(tq*NB+b)*NH + k]);
    sp[tq][q]=acc;
  }
  __syncthreads();
  if (tid < 64){
    float sv = (tid<TQ)? (sp[tid][0]+sp[tid][1]+sp[tid][2]+sp[tid][3]) : -1e30f;
    float mx = sv;
    #pragma unroll
    for (int o=32;o;o>>=1) mx = fmaxf(mx, __shfl_xor(mx,o));
    float e = (tid<TQ)? __expf(sv-mx) : 0.f;
    float sm = e;
    #pragma unroll
    for (int o=32;o;o>>=1) sm += __shfl_xor(sm,o);
    if (tid<TQ) alpha[tid] = e/sm;
  }
  __syncthreads();
  for (int j=tid; j<H2; j+=256){
    float acc=0.f;
    for (int tq=0;tq<TQ;tq++) acc += alpha[tq]*Hq[(size_t)(tq*NB+b)*H2 + j];
    wqb[b*H2+j] = acc;
    WRWQ[(size_t)b*H4 + H2 + j] = acc;
    WRWQ[(size_t)(NB+b)*H4 + H2 + j] = acc;
  }
}

// Pointer scores: sf = btW . tanh(aml + haW + wq) + btb.  One wave per (dir,t,b) row.
__global__ __launch_bounds__(256) void k_F(const float* __restrict__ AML, const float* __restrict__ AMLB,
      const float* __restrict__ HAW, const float* __restrict__ wqb,
      const float* __restrict__ btW, const float* __restrict__ btb, float* __restrict__ SF)
{
  const int gr = blockIdx.x*4 + (threadIdx.x>>6);
  const int lane = threadIdx.x & 63;
  const int dir = gr / (TP*NB);
  const int rem = gr % (TP*NB);
  const int b = rem % NB;
  const float* mrow = (dir? AMLB : AML) + (size_t)rem*H2;
  const float* hrow = HAW + (size_t)(dir*NB + b)*H2;
  const float* wrow = wqb + (size_t)b*H2;
  float acc = 0.f;
  for (int j = lane; j < H2; j += 64)
    acc += btW[j]*tanhf_(mrow[j] + hrow[j] + wrow[j]);
  #pragma unroll
  for (int o=32;o;o>>=1) acc += __shfl_xor(acc,o);
  if (lane==0) SF[gr] = acc + btb[0];
}

// Masked softmax over Tp, write dists (k>=1), compute wr (k<2).
__global__ __launch_bounds__(256) void k_beta(const float* __restrict__ SF, const float* __restrict__ Hr,
     const int* __restrict__ plens, float* __restrict__ WRWQ, float* __restrict__ dout, int kidx)
{
  const int wg = blockIdx.x; const int b = wg&63; const int dir = wg>>6;
  const int tid = threadIdx.x;
  __shared__ float sv[TP];
  __shared__ float red[256];
  const int len = plens[b];
  for (int t=tid;t<TP;t+=256) sv[t] = SF[(size_t)dir*TP*NB + t*NB + b];
  __syncthreads();
  float mx = -1e30f;
  for (int t=tid;t<len;t+=256) mx = fmaxf(mx, sv[t]);
  red[tid]=mx; __syncthreads();
  for (int o=128;o;o>>=1){ if (tid<o) red[tid]=fmaxf(red[tid],red[tid+o]); __syncthreads(); }
  mx = red[0]; __syncthreads();
  float sm=0.f;
  for (int t=tid;t<len;t+=256) sm += __expf(sv[t]-mx);
  red[tid]=sm; __syncthreads();
  for (int o=128;o;o>>=1){ if (tid<o) red[tid]+=red[tid+o]; __syncthreads(); }
  const float inv = 1.f/red[0];
  __syncthreads();
  for (int t=tid;t<TP;t+=256){
    const float bt = (t<len)? __expf(sv[t]-mx)*inv : 0.f;
    sv[t] = bt;
    if (kidx>0) dout[(size_t)(dir*2 + kidx-1)*TP*NB + (size_t)b*TP + t] = bt;
  }
  __syncthreads();
  if (kidx < 2){
    for (int j=tid;j<H2;j+=256){
      float acc=0.f;
      for (int t=0;t<TP;t++) acc += sv[t]*Hr[(size_t)(t*NB+b)*H2 + j];
      WRWQ[(size_t)(dir*NB+b)*H4 + j] = acc;
    }
  }
}

__global__ __launch_bounds__(256) void k_cell(const float* __restrict__ G, float* __restrict__ Sh, float* __restrict__ Sc){
  const int i = blockIdx.x*256+threadIdx.x;
  if (i >= 128*H2) return;
  const int r = i/H2, j = i%H2;
  const float* gr = G + (size_t)r*H8;
  const float gi=sigm(gr[j]), gf=sigm(gr[H2+j]), gg=tanhf_(gr[2*H2+j]), go=sigm(gr[3*H2+j]);
  const float c2 = gf*Sc[i] + gi*gg;
  Sc[i]=c2; Sh[i]=go*tanhf_(c2);
}

extern "C" void kernel_launch(void* const* d_in, const int* in_sizes, int n_in,
                              void* d_out, int out_size, void* d_ws, size_t ws_size,
                              hipStream_t stream)
{
  const int* p_ids = (const int*)d_in[0];
  const int* q_ids = (const int*)d_in[1];
  const int* p_len = (const int*)d_in[2];
  const int* q_len = (const int*)d_in[3];
  const float* emb    = (const float*)d_in[4];
  const float* preWih = (const float*)d_in[5];
  const float* preWhh = (const float*)d_in[6];
  const float* preBih = (const float*)d_in[7];
  const float* preBhh = (const float*)d_in[8];
  const float* aqW  = (const float*)d_in[9];
  const float* apW  = (const float*)d_in[10];
  const float* apB  = (const float*)d_in[11];
  const float* ahW  = (const float*)d_in[12];
  const float* alWp = (const float*)d_in[13];
  // d_in[14] al_b: softmax-invariant, unused
  const float* mWih = (const float*)d_in[15];
  const float* mWhh = (const float*)d_in[16];
  const float* mBih = (const float*)d_in[17];
  const float* mBhh = (const float*)d_in[18];
  const float* aqaW = (const float*)d_in[19];
  const float* alaW = (const float*)d_in[20];
  // d_in[21] ala_b: softmax-invariant, unused
  const float* amlW  = (const float*)d_in[22];
  const float* amlbW = (const float*)d_in[23];
  const float* aansW = (const float*)d_in[24];
  const float* aansB = (const float*)d_in[25];
  const float* btW = (const float*)d_in[26];
  const float* btB = (const float*)d_in[27];
  const float* ansWih = (const float*)d_in[28];
  const float* ansWhh = (const float*)d_in[29];
  const float* ansBih = (const float*)d_in[30];
  const float* ansBhh = (const float*)d_in[31];
  float* out = (float*)d_out;

  char* base = (char*)d_ws;
  size_t off = 0;
  auto alloc = [&](size_t bytes)->char*{ char* r = base+off; off += (bytes+255)&~(size_t)255; return r; };
  float* BIG  = (float*)alloc((size_t)TP*NB*H4*4);   // XWp(450w) -> HPW(600w) -> AML|AMLB
  float* XWQ  = (float*)alloc((size_t)TQ*NB*450*4);
  float* HP   = (float*)alloc((size_t)TP*NB*H2*4);
  float* HQ   = (float*)alloc((size_t)TQ*NB*H2*4);
  float* ATTQ = (float*)alloc((size_t)TQ*NB*NH*4);
  float* APP  = (float*)alloc((size_t)TP*NB*NH*4);
  float* HR   = (float*)alloc((size_t)TP*NB*H2*4);
  float* AQA  = (float*)alloc((size_t)TQ*NB*NH*4);
  float* QWf  = (float*)alloc((size_t)TQ*NB*H4*4);
  float* SFb  = (float*)alloc((size_t)2*TP*NB*4);
  float* WRWQ = (float*)alloc((size_t)128*H4*4);
  float* HAW  = (float*)alloc((size_t)128*H2*4);
  float* Gb   = (float*)alloc((size_t)128*H8*4);
  float* Sh   = (float*)alloc((size_t)128*H2*4);
  float* Sc   = (float*)alloc((size_t)128*H2*4);
  float* WQB  = (float*)alloc((size_t)NB*H2*4);
  unsigned short* whh_b  = (unsigned short*)alloc((size_t)H4*KP150*2);
  unsigned short* ah_b   = (unsigned short*)alloc((size_t)NH*KP150*2);
  unsigned short* mwhh_b = (unsigned short*)alloc((size_t)H4*KP150*2);
  unsigned short* QWT    = (unsigned short*)alloc((size_t)NB*H4*64*2);
  float* AML  = BIG;
  float* AMLB = BIG + (size_t)TP*NB*H2;

  dim3 blk(256);
  k_prep<<<(H4*KP150+255)/256, blk, 0, stream>>>(preWhh, ahW, mWhh, whh_b, ah_b, mwhh_b);
  // XW = emb[ids] @ preWih^T + bih + bhh   (only i,f,g gate columns: N=450)
  { dim3 g((450+127)/128, (TP*NB+127)/128);
    k_gemm<<<g, blk, 0, stream>>>(emb, p_ids, preWih, H2, preBih, preBhh, BIG, TP*NB, 450, H2, 0); }
  { dim3 g((450+127)/128, (TQ*NB+127)/128);
    k_gemm<<<g, blk, 0, stream>>>(emb, q_ids, preWih, H2, preBih, preBhh, XWQ, TQ*NB, 450, H2, 0); }
  k_pre_scan<<<256, dim3(512), 0, stream>>>(BIG, XWQ, whh_b, p_len, q_len, HP, HQ);
  { dim3 g((NH+127)/128, (TQ*NB+127)/128);
    k_gemm<<<g,blk,0,stream>>>(HQ, nullptr, aqW, H2, nullptr, nullptr, ATTQ, TQ*NB, NH, H2, 0); }
  { dim3 g((NH+127)/128, (TP*NB+127)/128);
    k_gemm<<<g,blk,0,stream>>>(HP, nullptr, apW, H2, apB, nullptr, APP, TP*NB, NH, H2, 0); }
  { dim3 g((H4+127)/128, (TP*NB+127)/128);
    k_gemm<<<g,blk,0,stream>>>(HP, nullptr, mWih, H4, mBih, mBhh, BIG, TP*NB, H4, H2, 0); }
  { dim3 g((NH+127)/128, (TQ*NB+127)/128);
    k_gemm<<<g,blk,0,stream>>>(HQ, nullptr, aqaW, H2, nullptr, nullptr, AQA, TQ*NB, NH, H2, 0); }
  // QWf[(tq,b), j] = Hq . mWih_right_j   (step-invariant attention projection)
  { dim3 g((H4+127)/128, (TQ*NB+127)/128);
    k_gemm<<<g,blk,0,stream>>>(HQ, nullptr, mWih + H2, H4, nullptr, nullptr, QWf, TQ*NB, H4, H2, 0); }
  k_qwt<<<(NB*H4*64+255)/256, blk, 0, stream>>>(QWf, QWT);
  k_wq<<<NB, blk, 0, stream>>>(AQA, HQ, alaW, WQB, WRWQ);
  k_match<<<dim3(128), dim3(1024), 0, stream>>>(ATTQ, APP, BIG, QWT, mwhh_b, ah_b, alWp, p_len, HR);
  { dim3 g((H2+127)/128, (TP*NB+127)/128);
    k_gemm<<<g,blk,0,stream>>>(HR, nullptr, amlW,  H2, nullptr, nullptr, AML,  TP*NB, H2, H2, 0);
    k_gemm<<<g,blk,0,stream>>>(HR, nullptr, amlbW, H2, nullptr, nullptr, AMLB, TP*NB, H2, H2, 0); }
  hipMemsetAsync(Sh, 0, (size_t)128*H2*4, stream);
  hipMemsetAsync(Sc, 0, (size_t)128*H2*4, stream);
  for (int k=0;k<3;k++){
    { dim3 g((H2+127)/128, 1);
      k_gemm<<<g,blk,0,stream>>>(Sh, nullptr, aansW, H2, aansB, nullptr, HAW, 128, H2, H2, 0); }
    k_F<<<(2*TP*NB)/4, blk, 0, stream>>>(AML, AMLB, HAW, WQB, btW, btB, SFb);
    k_beta<<<128, blk, 0, stream>>>(SFb, HR, p_len, WRWQ, out, k);
    if (k<2){
      { dim3 g((H8+127)/128, 1);
        k_gemm<<<g,blk,0,stream>>>(WRWQ, nullptr, ansWih, H4, ansBih, ansBhh, Gb, 128, H8, H4, 0); }
      { dim3 g((H8+127)/128, 1);
        k_gemm<<<g,blk,0,stream>>>(Sh, nullptr, ansWhh, H2, nullptr, nullptr, Gb, 128, H8, H2, 1); }
      k_cell<<<(128*H2+255)/256, blk, 0, stream>>>(Gb, Sh, Sc);
    }
  }
}